// Round 8
// baseline (372.765 us; speedup 1.0000x reference)
//
#include <hip/hip_runtime.h>
#include <stdint.h>

// out = x @ tanh(block_diag(blocks)) -- 16 blocks of 256x256. ALL BUFFERS FLOAT32.
// Kernel 1: tanh_pack -> wsT in CHUNKED+SWIZZLED bf16 layout, per block j (128 KB):
//   byte(n,k) = (k>>6)*32768 + n*128 + ((2*(k&63)) ^ ((n&7)<<4))
// Kernel 2: bdgemm8 -- ZERO LDS, ZERO barriers. Grid 128x16, 256-thr WGs, 4 waves
//   each owning 16 rows x 256 cols. B-fragments read directly from wsT (2 MB --
//   L2-resident per XCD after first touch; ~200cy, not 900cy HBM). launch_bounds
//   (256,4) caps VGPR at 128 -> 4 waves/SIMD = 50% occupancy (2.7x R7 residency).
//   A double-buffered in regs; swapped-operand MFMA -> contiguous float4 stores.

typedef float floatx4 __attribute__((ext_vector_type(4)));
typedef __bf16 bf16x8 __attribute__((ext_vector_type(8)));

#define LDX 4096
#define NBLK 16
#define BS 256

__device__ __forceinline__ unsigned int f2bf(float f) {
  union { float f; unsigned int i; } x;
  x.f = f;
  unsigned int r = x.i + 0x7FFFu + ((x.i >> 16) & 1u);  // RNE
  return r >> 16;
}

__device__ __forceinline__ bf16x8 pack8(const float4& a, const float4& b) {
  union { uint4 u; bf16x8 h; } v;
  v.u.x = f2bf(a.x) | (f2bf(a.y) << 16);
  v.u.y = f2bf(a.z) | (f2bf(a.w) << 16);
  v.u.z = f2bf(b.x) | (f2bf(b.y) << 16);
  v.u.w = f2bf(b.z) | (f2bf(b.w) << 16);
  return v.h;
}

// wsT: per j, chunked (k/64) rows of 128B with XOR-swizzled k-position.
__global__ __launch_bounds__(256) void tanh_pack(const float* __restrict__ blocks,
                                                 unsigned short* __restrict__ wsT) {
  __shared__ float tile[64][65];  // [k][n], +1 pad for conflict-free column reads
  const int t = threadIdx.x;
  const int tc = blockIdx.x, tr = blockIdx.y, j = blockIdx.z;
  const float* src = blocks + (size_t)(j * BS + tr * 64) * LDX + j * BS + tc * 64;
#pragma unroll
  for (int it = 0; it < 8; ++it) {
    int v = it * 256 + t;
    int row = v >> 5;       // k within tile, 0..63
    int c2 = (v & 31) * 2;  // n within tile, even
    float2 f = *(const float2*)(src + (size_t)row * LDX + c2);
    tile[row][c2] = tanhf(f.x);
    tile[row][c2 + 1] = tanhf(f.y);
  }
  __syncthreads();
  // chunk index == tr (64 k per chunk). Write swizzled dwords (pair k2,k2+1).
  unsigned char* dstj =
      (unsigned char*)wsT + (size_t)j * 131072 + (size_t)tr * 32768;
#pragma unroll
  for (int it = 0; it < 8; ++it) {
    int v = it * 256 + t;
    int nn = v >> 5;        // n within tile
    int k2 = (v & 31) * 2;  // k-local within chunk, even
    int n = tc * 64 + nn;   // 0..255
    unsigned int pair = f2bf(tile[k2][nn]) | (f2bf(tile[k2 + 1][nn]) << 16);
    unsigned int off = (unsigned)n * 128 + (((unsigned)(k2 * 2)) ^ (((unsigned)(n & 7)) << 4));
    *(unsigned int*)(dstj + off) = pair;  // coalesced within each 128B row
  }
}

// grid dim3(128, 16): bx = 64-row group, by = j. 4 waves/WG, 16 rows/wave, no LDS.
__global__ __launch_bounds__(256, 4) void bdgemm8(const float* __restrict__ x,
                                                  const unsigned short* __restrict__ wsT,
                                                  float* __restrict__ out) {
  const int t = threadIdx.x;
  const int lane = t & 63;
  const int wave = t >> 6;    // 0..3
  const int rg = blockIdx.x;  // 0..127
  const int j = blockIdx.y;   // 0..15

  const int fr = lane & 15;      // fragment row (A m / B n within 16)
  const int kq = lane >> 4;      // k subgroup (x8)
  const int sw = (fr & 7) << 4;  // XOR swizzle (bits 4-6) for B reads

  const int row = rg * 64 + wave * 16 + fr;
  const float* ap = x + (size_t)row * LDX + j * BS + kq * 8;
  const char* wsj = (const char*)wsT + (size_t)j * 131072 + fr * 128;

  float4 pa[2][2];  // A double-buffer: {lo,hi} of one k-chunk for row fr
  pa[0][0] = *(const float4*)(ap);
  pa[0][1] = *(const float4*)(ap + 4);

  floatx4 acc[16];
#pragma unroll
  for (int i = 0; i < 16; ++i) acc[i] = (floatx4){0.f, 0.f, 0.f, 0.f};

  // 8 k-chunks of 32. B-fragment loads hit L2 (wsT is 2 MB, XCD-resident).
#pragma unroll
  for (int c = 0; c < 8; ++c) {
    if (c + 1 < 8) {  // prefetch next A chunk into the other buffer (static idx)
      const float* p = ap + (c + 1) * 32;
      pa[(c + 1) & 1][0] = *(const float4*)(p);
      pa[(c + 1) & 1][1] = *(const float4*)(p + 4);
    }
    bf16x8 af = pack8(pa[c & 1][0], pa[c & 1][1]);  // A[m=fr][k=c*32+kq*8..+7]
    const char* bb = wsj + (c >> 1) * 32768 + (((c & 1) * 64 + kq * 16) ^ sw);
#pragma unroll
    for (int ni = 0; ni < 16; ++ni) {
      bf16x8 bf = *(const bf16x8*)(bb + ni * 2048);  // B[n=ni*16+fr][k-slice]
      // SWAPPED operands (R6/R7-verified): lane (fr,kq) -> D[m=fr][n=ni*16+kq*4+r]
      acc[ni] = __builtin_amdgcn_mfma_f32_16x16x32_bf16(bf, af, acc[ni], 0, 0, 0);
    }
  }

  // contiguous float4 store per ni: out[row][j*256 + ni*16 + kq*4 .. +3]
  float* op0 = out + (size_t)row * LDX + j * BS + kq * 4;
#pragma unroll
  for (int ni = 0; ni < 16; ++ni)
    *(floatx4*)(op0 + ni * 16) = acc[ni];
}

// Fallback (no workspace): B from raw f32 blocks with inline tanh.
template <int BSTR>
__global__ __launch_bounds__(256) void bdgemm_fused(const float* __restrict__ x,
                                                    const float* __restrict__ bg,
                                                    float* __restrict__ out) {
  __shared__ unsigned short As[64 * 32];
  __shared__ unsigned short Bsf[256 * BSTR];
  const int t = threadIdx.x;
  const int lane = t & 63;
  const int wave = t >> 6;
  const int mtile = blockIdx.x;
  const int j = blockIdx.y;
  const int m0 = mtile * 64;
  const float* xg = x + (size_t)m0 * LDX + j * BS;
  const int srow = t >> 2;
  const int scol = (t & 3) * 8;
  const int wn = wave * 64;
  const int fr = lane & 15;
  const int fq = (lane >> 4) * 8;

  floatx4 acc[4][4];
#pragma unroll
  for (int a = 0; a < 4; ++a)
#pragma unroll
    for (int b = 0; b < 4; ++b) acc[a][b] = (floatx4){0.f, 0.f, 0.f, 0.f};

  for (int kt = 0; kt < 8; ++kt) {
    const int k0 = kt * 32;
    const float* ap = xg + (size_t)srow * LDX + k0 + scol;
    float4 a0 = *(const float4*)(ap);
    float4 a1 = *(const float4*)(ap + 4);
    uint4 pk;
    pk.x = f2bf(a0.x) | (f2bf(a0.y) << 16);
    pk.y = f2bf(a0.z) | (f2bf(a0.w) << 16);
    pk.z = f2bf(a1.x) | (f2bf(a1.y) << 16);
    pk.w = f2bf(a1.z) | (f2bf(a1.w) << 16);
    *(uint4*)(As + t * 8) = pk;
#pragma unroll
    for (int i = 0; i < 32; ++i) {
      const int idx = i * 256 + t;
      const int kk = idx >> 8;
      const int nn = idx & 255;
      float v = tanhf(bg[(size_t)(j * BS + k0 + kk) * LDX + j * BS + nn]);
      Bsf[nn * BSTR + kk] = (unsigned short)f2bf(v);
    }
    __syncthreads();
    bf16x8 af[4], bfm[4];
#pragma unroll
    for (int i = 0; i < 4; ++i) {
      af[i] = *(const bf16x8*)(As + (i * 16 + fr) * 32 + fq);
      bfm[i] = *(const bf16x8*)(Bsf + (wn + i * 16 + fr) * BSTR + fq);
    }
#pragma unroll
    for (int mi = 0; mi < 4; ++mi)
#pragma unroll
      for (int ni = 0; ni < 4; ++ni)
        acc[mi][ni] =
            __builtin_amdgcn_mfma_f32_16x16x32_bf16(af[mi], bfm[ni], acc[mi][ni], 0, 0, 0);
    __syncthreads();
  }
  const int r0 = (lane >> 4) * 4;
  const int ocol = j * BS + wn + fr;
#pragma unroll
  for (int mi = 0; mi < 4; ++mi)
#pragma unroll
    for (int ni = 0; ni < 4; ++ni) {
      float* op = out + (size_t)(m0 + mi * 16 + r0) * LDX + ocol + ni * 16;
#pragma unroll
      for (int r = 0; r < 4; ++r) op[(size_t)r * LDX] = acc[mi][ni][r];
    }
}

extern "C" void kernel_launch(void* const* d_in, const int* in_sizes, int n_in,
                              void* d_out, int out_size, void* d_ws, size_t ws_size,
                              hipStream_t stream) {
  const float* x = (const float*)d_in[0];       // 8192x4096 f32
  const float* blocks = (const float*)d_in[1];  // 4096x4096 f32
  // d_in[2] (mask) unused: block structure is static, tanh(0)=0.
  float* out = (float*)d_out;

  const size_t need = (size_t)NBLK * BS * BS * sizeof(unsigned short);  // 2 MB
  if (d_ws != nullptr && ws_size >= need) {
    unsigned short* wsT = (unsigned short*)d_ws;
    tanh_pack<<<dim3(4, 4, NBLK), 256, 0, stream>>>(blocks, wsT);
    bdgemm8<<<dim3(128, NBLK), 256, 0, stream>>>(x, wsT, out);
  } else {
    bdgemm_fused<40><<<dim3(128, NBLK), 256, 0, stream>>>(x, blocks, out);
  }
}